// Round 5
// baseline (5273.144 us; speedup 1.0000x reference)
//
#include <hip/hip_runtime.h>
#include <hip/hip_bf16.h>

#define B_ 256
#define S_ 512
#define H_ 1024
#define C_ 10

typedef unsigned long long u64;
typedef __attribute__((ext_vector_type(8))) short s8v;      // 8 bf16 (4 VGPRs) - MFMA A/B frag
typedef __attribute__((ext_vector_type(4))) float f4v;      // MFMA C/D frag

// ---------------- workspace layout (bytes) ----------------
// [0, 4096)        : flags[256 blocks][4 waves] (u32), zeroed per launch
// [4096, 5120)     : epoch[8 XCDs] (u32, 128 B apart), zeroed
// [5120, 5152)     : leader[8 XCDs] (int), zeroed
// [8192, +512K)    : xT  (S x B fp32)
// [+512K, +512K)   : h0  (B x H bf16), zeroed per launch
// [+512K, +512K)   : h1
// [+512K, +8M)     : Wp  (packed bf16 weights, fragment-linear, MFMA A operand)
#define HDR_ 8192

__global__ void prep_w(const float* __restrict__ wg, const float* __restrict__ wi,
                       const float* __restrict__ wf, const float* __restrict__ wo,
                       __hip_bfloat16* __restrict__ Wp) {
    int idx = blockIdx.x * 256 + threadIdx.x;        // 524288 groups of 8
    int g   = idx >> 17;
    int rem = idx & 131071;
    int o   = rem >> 7;                              // out col 0..1023
    int kg  = rem & 127;                             // k0 = kg*8
    const float* src = (g == 0 ? wg : g == 1 ? wi : g == 2 ? wf : wo) + o * H_ + kg * 8;
    int kc   = kg >> 2;
    int quad = kg & 3;
    int lane = quad * 16 + (o & 15);
    int ot   = o >> 4;
    int blk  = (g * 64 + ot) * 32 + kc;
    __hip_bfloat16* dst = Wp + blk * 512 + lane * 8;
#pragma unroll
    for (int j = 0; j < 8; ++j) dst[j] = __float2bfloat16(src[j]);
}

__global__ void prep_x(const float* __restrict__ x, float* __restrict__ xT) {
    int i = blockIdx.x * 256 + threadIdx.x;          // 131072
    int t = i >> 8, b = i & 255;
    xT[i] = x[b * S_ + t];
}

__device__ __forceinline__ float sigmoid_f(float x) { return 1.0f / (1.0f + __expf(-x)); }
__device__ __forceinline__ float tanh_f(float x)    { return 2.0f / (1.0f + __expf(-2.0f * x)) - 1.0f; }

__device__ __forceinline__ float bf2f(unsigned short u) {
    union { unsigned i; float f; } x; x.i = ((unsigned)u) << 16; return x.f;
}
__device__ __forceinline__ unsigned short f2bf(float f) {
    union { __hip_bfloat16 h; unsigned short s; } x; x.h = __float2bfloat16(f); return x.s;
}

__device__ __forceinline__ void waitcnt_vm0() { asm volatile("s_waitcnt vmcnt(0)" ::: "memory"); }
__device__ __forceinline__ void inv_l1()      { asm volatile("buffer_inv" ::: "memory"); }
__device__ __forceinline__ void inv_l2()      { asm volatile("buffer_inv sc1" ::: "memory"); }

// HW_REG_XCC_ID = 20, offset 0, size 32 -> imm = 20 | (31<<11)
__device__ __forceinline__ int xcc_id() {
    return (int)(__builtin_amdgcn_s_getreg(20 | (31 << 11)) & 7u);
}

// leader wave: wait until ALL 1024 wave-flags >= tgt (16 flags/lane via 8 u64 loads)
__device__ __forceinline__ void leader_wait_flags(const u64* f64, int l, unsigned tgt) {
    for (;;) {
        unsigned mn = 0xffffffffu;
#pragma unroll
        for (int j = 0; j < 8; ++j) {
            u64 v = __hip_atomic_load(f64 + 8 * l + j, __ATOMIC_RELAXED, __HIP_MEMORY_SCOPE_AGENT);
            unsigned a = (unsigned)v, b = (unsigned)(v >> 32);
            mn = min(mn, min(a, b));
        }
        if (__ballot(mn < tgt) == 0ull) break;
        __builtin_amdgcn_s_sleep(1);
    }
}

__device__ __forceinline__ void wait_epoch(const unsigned* ep, unsigned tgt) {
    for (;;) {
        unsigned e = __hip_atomic_load(ep, __ATOMIC_RELAXED, __HIP_MEMORY_SCOPE_AGENT);
        if (e >= tgt) break;
        __builtin_amdgcn_s_sleep(1);
    }
}

__global__ __launch_bounds__(256, 1) void lstm_main(
    const float* __restrict__ xT,
    const float* __restrict__ wgx, const float* __restrict__ wix,
    const float* __restrict__ wfx, const float* __restrict__ wox,
    const float* __restrict__ bg,  const float* __restrict__ bi,
    const float* __restrict__ bf,  const float* __restrict__ bo,
    const __hip_bfloat16* __restrict__ Wp,
    __hip_bfloat16* __restrict__ h0, __hip_bfloat16* __restrict__ h1,
    const float* __restrict__ wph, const float* __restrict__ bp,
    float* __restrict__ out,
    unsigned* __restrict__ flags, unsigned* __restrict__ epoch, int* __restrict__ leader)
{
    // weights LDS-stationary: 4 gates x 32 kc x 64 lanes x 16B = 128 KB
    __shared__ s8v Wlds[4 * 32 * 64];

    const int tid  = threadIdx.x;
    const int wgid = blockIdx.x;         // 256 blocks
    // XCD-affinity remap (perf heuristic under round-robin dispatch):
    // group m lives on XCDs {2m, 2m+1}
    const int m    = (wgid & 7) >> 1;                 // batch group 0..3 (64 rows)
    const int n    = ((wgid >> 3) << 1) | (wgid & 1); // out-tile 0..63 (16 cols/gate)
    const int w    = tid >> 6;           // wave 0..3 (batch sub-tile)
    const int l    = tid & 63;
    const int quad = l >> 4;
    const int l16  = l & 15;
    const int b    = m * 64 + w * 16 + l16;  // this lane's batch row (B-frag col / D col)
    const int out0 = n * 16 + quad * 4;      // first of this lane's 4 hidden cols (D rows)

    // stage this block's weights into LDS (coalesced 16B loads)
    {
        const s8v* Wv = (const s8v*)Wp;
#pragma unroll
        for (int j = 0; j < 32; ++j) {
            int idx = j * 256 + tid;             // 0..8191
            int g   = idx >> 11;
            int rem = idx & 2047;                // kc*64 + lane
            Wlds[g * 2048 + rem] = Wv[((g * 64 + n) * 32) * 64 + rem];
        }
    }

    // elect one leader block per physical XCD
    const int x = xcc_id();
    unsigned* ep = epoch + x * 32;           // 128 B apart
    int am_leader = 0;
    if (w == 0) {
        int v = 0;
        if (l == 0) v = (atomicCAS(leader + x, 0, wgid + 1) == 0) ? 1 : 0;
        am_leader = __shfl(v, 0, 64);
    }

    // per-lane gate params for the 4 consecutive hidden cols
    float wxg[4], wxi[4], wxf[4], wxo[4], bbg[4], bbi[4], bbf[4], bbo[4];
    *(float4*)wxg = *(const float4*)(wgx + out0);
    *(float4*)wxi = *(const float4*)(wix + out0);
    *(float4*)wxf = *(const float4*)(wfx + out0);
    *(float4*)wxo = *(const float4*)(wox + out0);
    *(float4*)bbg = *(const float4*)(bg + out0);
    *(float4*)bbi = *(const float4*)(bi + out0);
    *(float4*)bbf = *(const float4*)(bf + out0);
    *(float4*)bbo = *(const float4*)(bo + out0);

    float cs[4] = {0.f, 0.f, 0.f, 0.f};     // persistent cell state

    const u64* f64   = (const u64*)flags;
    unsigned* myflag = flags + (wgid << 2) + w;

    __syncthreads();                         // LDS weights ready (only barrier in kernel)

    for (int t = 0; t < S_; ++t) {
        const __hip_bfloat16* hin  = (t & 1) ? h1 : h0;
        __hip_bfloat16*       hout = (t & 1) ? h0 : h1;

        if (am_leader) {
            // one L2 invalidate per XCD per step, then publish epoch
            leader_wait_flags(f64, l, (unsigned)t);
            inv_l2(); inv_l1(); waitcnt_vm0();
            if (l == 0)
                __hip_atomic_store(ep, (unsigned)(t + 1), __ATOMIC_RELAXED, __HIP_MEMORY_SCOPE_AGENT);
        } else {
            wait_epoch(ep, (unsigned)(t + 1));
            inv_l1(); waitcnt_vm0();         // L1-only: keep XCD L2 warm
        }

        float xa = xT[t * B_ + b];

        // h B-fragments via normal cached loads: fresh (post-inv) L2 broadcast
        const s8v* hb = (const s8v*)(hin + (size_t)b * H_) + quad;
        s8v hfrag[32];
#pragma unroll
        for (int kc = 0; kc < 32; ++kc) hfrag[kc] = hb[kc * 4];

        f4v acc0 = {0.f, 0.f, 0.f, 0.f}, acc1 = acc0, acc2 = acc0, acc3 = acc0;
#pragma unroll
        for (int kc = 0; kc < 32; ++kc) {
            s8v hv = hfrag[kc];
            acc0 = __builtin_amdgcn_mfma_f32_16x16x32_bf16(Wlds[0 * 2048 + kc * 64 + l], hv, acc0, 0, 0, 0);
            acc1 = __builtin_amdgcn_mfma_f32_16x16x32_bf16(Wlds[1 * 2048 + kc * 64 + l], hv, acc1, 0, 0, 0);
            acc2 = __builtin_amdgcn_mfma_f32_16x16x32_bf16(Wlds[2 * 2048 + kc * 64 + l], hv, acc2, 0, 0, 0);
            acc3 = __builtin_amdgcn_mfma_f32_16x16x32_bf16(Wlds[3 * 2048 + kc * 64 + l], hv, acc3, 0, 0, 0);
        }

        // epilogue: D row (quad*4+r) = hidden col out0+r, D col (l16) = batch b
        unsigned short hs[4];
#pragma unroll
        for (int r = 0; r < 4; ++r) {
            float pg = acc0[r] + xa * wxg[r] + bbg[r];
            float pi = acc1[r] + xa * wxi[r] + bbi[r];
            float pf = acc2[r] + xa * wxf[r] + bbf[r];
            float po = acc3[r] + xa * wxo[r] + bbo[r];
            float gv = tanh_f(pg);
            float iv = sigmoid_f(pi);
            float fv = sigmoid_f(pf);
            float ov = sigmoid_f(po);
            float cn = gv * iv + cs[r] * fv;
            cs[r] = cn;
            hs[r] = f2bf(tanh_f(cn) * ov);
        }
        union { unsigned short s[4]; u64 q; } hp_;
        hp_.s[0] = hs[0]; hp_.s[1] = hs[1]; hp_.s[2] = hs[2]; hp_.s[3] = hs[3];
        // 8B write-through (LLC) store, then per-wave release: drain + flag
        __hip_atomic_store((u64*)(hout + b * H_ + out0), hp_.q,
                           __ATOMIC_RELAXED, __HIP_MEMORY_SCOPE_AGENT);
        waitcnt_vm0();                       // h store ack'ed at LLC
        if (l == 0)
            __hip_atomic_store(myflag, (unsigned)(t + 1), __ATOMIC_RELAXED, __HIP_MEMORY_SCOPE_AGENT);
    }

    // tail: one more protocol round so final h (in h0) is visible via cached loads
    if (am_leader) {
        leader_wait_flags(f64, l, (unsigned)S_);
        inv_l2(); inv_l1(); waitcnt_vm0();
        if (l == 0)
            __hip_atomic_store(ep, (unsigned)(S_ + 1), __ATOMIC_RELAXED, __HIP_MEMORY_SCOPE_AGENT);
    } else {
        wait_epoch(ep, (unsigned)(S_ + 1));
        inv_l1(); waitcnt_vm0();
    }

    // projection restricted to own group's rows: out[row][cc], rows [64m, 64m+64)
    const __hip_bfloat16* hf = h0;           // t=511 (odd) wrote h0
    int wig = n * 4 + w;                     // wave index in group, 0..255
    for (int p = wig; p < 64 * C_; p += 256) {
        int row = m * 64 + p / C_;
        int cc  = p % C_;
        const u64* hr = (const u64*)(hf + row * H_);
        const float* wr = wph + cc * H_;
        float acc = 0.f;
#pragma unroll
        for (int j = 0; j < 4; ++j) {
            int k = j * 256 + l * 4;
            union { u64 q; unsigned short s[4]; } u_; u_.q = hr[k >> 2];
            float4 wv = *(const float4*)(wr + k);
            acc += bf2f(u_.s[0]) * wv.x + bf2f(u_.s[1]) * wv.y
                 + bf2f(u_.s[2]) * wv.z + bf2f(u_.s[3]) * wv.w;
        }
#pragma unroll
        for (int off = 32; off > 0; off >>= 1) acc += __shfl_down(acc, off, 64);
        if (l == 0) out[row * C_ + cc] = acc + bp[cc];
    }
}

extern "C" void kernel_launch(void* const* d_in, const int* in_sizes, int n_in,
                              void* d_out, int out_size, void* d_ws, size_t ws_size,
                              hipStream_t stream) {
    const float* xx  = (const float*)d_in[0];
    const float* wgx = (const float*)d_in[1];
    const float* wix = (const float*)d_in[2];
    const float* wfx = (const float*)d_in[3];
    const float* wox = (const float*)d_in[4];
    const float* wgh = (const float*)d_in[5];
    const float* wih = (const float*)d_in[6];
    const float* wfh = (const float*)d_in[7];
    const float* woh = (const float*)d_in[8];
    const float* wph = (const float*)d_in[9];
    const float* bg  = (const float*)d_in[10];
    const float* bi  = (const float*)d_in[11];
    const float* bf  = (const float*)d_in[12];
    const float* bo  = (const float*)d_in[13];
    const float* bp  = (const float*)d_in[14];
    float* out = (float*)d_out;

    char* ws = (char*)d_ws;
    unsigned*       flags  = (unsigned*)ws;                 // 4 KB
    unsigned*       epoch  = (unsigned*)(ws + 4096);        // 8 x u32, 128 B apart
    int*            leader = (int*)(ws + 5120);             // 8 ints
    float*          xT = (float*)(ws + HDR_);
    __hip_bfloat16* h0 = (__hip_bfloat16*)(ws + HDR_ + 524288);
    __hip_bfloat16* h1 = (__hip_bfloat16*)(ws + HDR_ + 2 * 524288);
    __hip_bfloat16* Wp = (__hip_bfloat16*)(ws + HDR_ + 3 * 524288);

    hipMemsetAsync(ws, 0, HDR_, stream);                  // flags + epoch + leader = 0
    hipMemsetAsync(h0, 0, 524288, stream);                // h_0 = 0
    prep_x<<<512, 256, 0, stream>>>(xx, xT);
    prep_w<<<2048, 256, 0, stream>>>(wgh, wih, wfh, woh, Wp);
    lstm_main<<<256, 256, 0, stream>>>(xT, wgx, wix, wfx, wox, bg, bi, bf, bo,
                                       Wp, h0, h1, wph, bp, out, flags, epoch, leader);
}